// Round 4
// baseline (403.919 us; speedup 1.0000x reference)
//
#include <hip/hip_runtime.h>
#include <hip/hip_cooperative_groups.h>
#include <math.h>

namespace cg = cooperative_groups;

#define HH 96
#define WW 320
#define NP 8

typedef _Float16 half8_t  __attribute__((ext_vector_type(8)));
typedef _Float16 half4_t  __attribute__((ext_vector_type(4)));
typedef float    floatx16 __attribute__((ext_vector_type(16)));

struct ShiftInfo {
    int   s0[NP];
    float wa[NP];
    float wb[NP];
    int   rows[16];
};

// ---------------------------------------------------------------------------
// Phase 0: input transpose+cvt  X[b][ci][y][x] -> Xt[b][y][x][ci] (f16)
//          weight cvt to MFMA-fragment-native layout:
//          Wlay[pos][mt][ks][i31][h][j] = W[co=mt*32+i31][ci=ks*16+h*8+j][pos]
//          so a wave's fragment load is base + lane*16B (fully coalesced).
// ---------------------------------------------------------------------------
__device__ __forceinline__ void prep_phase(
    const float* __restrict__ X, const float* __restrict__ W1,
    const float* __restrict__ W2, _Float16* __restrict__ Xt,
    _Float16* __restrict__ Wf, _Float16* sh, int NB)
{
    const int t = threadIdx.x;
    for (int task = blockIdx.x; task < 402; task += NB) {
        if (task < 384) {
            const int y = task % HH, b = task / HH;
            _Float16* Ls = sh;                       // [64][324]
            __syncthreads();
            for (int u = t; u < 64 * 80; u += 256) {
                int ci = u / 80;
                int x4 = (u - ci * 80) * 4;
                float4 v = *(const float4*)&X[((size_t)(b * 64 + ci) * HH + y) * WW + x4];
                half4_t hv = { (_Float16)v.x, (_Float16)v.y, (_Float16)v.z, (_Float16)v.w };
                *(half4_t*)&Ls[ci * 324 + x4] = hv;
            }
            __syncthreads();
            const int ci8 = t & 7, xg = t >> 3;
            for (int it = 0; it < 10; ++it) {
                int x = xg + 32 * it;
                half8_t o;
#pragma unroll
                for (int j = 0; j < 8; ++j) o[j] = Ls[(ci8 * 8 + j) * 324 + x];
                *(half8_t*)&Xt[((size_t)(b * HH + y) * WW + x) * 64 + ci8 * 8] = o;
            }
        } else {
            const int k = task - 384;               // 0..17
            const int layer = k / 9, pos = k - layer * 9;
            const float* Ws = layer ? W2 : W1;
            _Float16* Wd = Wf + layer * 36864 + pos * 4096;
            for (int u = t; u < 4096; u += 256) {
                int mt  = u >> 11;
                int ks  = (u >> 9) & 3;
                int i31 = (u >> 4) & 31;
                int h   = (u >> 3) & 1;
                int j   = u & 7;
                int co  = mt * 32 + i31;
                int ci  = ks * 16 + h * 8 + j;
                Wd[u] = (_Float16)Ws[((size_t)co * 64 + ci) * 9 + pos];
            }
        }
    }
}

// ---------------------------------------------------------------------------
// conv core: NPOS compile-time (9 = full 3x3, 3 = top 1x3)
// ---------------------------------------------------------------------------
template<int MODE, int NPOS>
__device__ __forceinline__ void conv_core(
    const _Float16* xb, const _Float16* wp0, floatx16 (&acc)[2][2])
{
#pragma unroll
    for (int pos = 0; pos < NPOS; ++pos) {
        const int ky = pos / 3, kx = pos - ky * 3;
        const _Float16* wp = wp0 + pos * 4096;
#pragma unroll
        for (int ks = 0; ks < 4; ++ks) {
            half8_t wfr0 = *(const half8_t*)(wp + ks * 512);
            half8_t wfr1 = *(const half8_t*)(wp + 2048 + ks * 512);
            half8_t xfr0 = *(const half8_t*)(xb + (ky * 66 + kx) * 72 + ks * 16);
            half8_t xfr1 = *(const half8_t*)(xb + (ky * 66 + kx + 32) * 72 + ks * 16);
            if (MODE == 1) {
                acc[0][0] = __builtin_amdgcn_mfma_f32_32x32x16_f16(xfr0, wfr0, acc[0][0], 0, 0, 0);
                acc[0][1] = __builtin_amdgcn_mfma_f32_32x32x16_f16(xfr0, wfr1, acc[0][1], 0, 0, 0);
                acc[1][0] = __builtin_amdgcn_mfma_f32_32x32x16_f16(xfr1, wfr0, acc[1][0], 0, 0, 0);
                acc[1][1] = __builtin_amdgcn_mfma_f32_32x32x16_f16(xfr1, wfr1, acc[1][1], 0, 0, 0);
            } else {
                acc[0][0] = __builtin_amdgcn_mfma_f32_32x32x16_f16(wfr0, xfr0, acc[0][0], 0, 0, 0);
                acc[0][1] = __builtin_amdgcn_mfma_f32_32x32x16_f16(wfr0, xfr1, acc[0][1], 0, 0, 0);
                acc[1][0] = __builtin_amdgcn_mfma_f32_32x32x16_f16(wfr1, xfr0, acc[1][0], 0, 0, 0);
                acc[1][1] = __builtin_amdgcn_mfma_f32_32x32x16_f16(wfr1, xfr1, acc[1][1], 0, 0, 0);
            }
        }
    }
}

// ---------------------------------------------------------------------------
// Phase 1/3: MFMA implicit-GEMM conv (ext rows rg<24, top-shift rows rg>=24)
// MODE 1: D[m=x][n=co] -> [b][OH][320][64];  MODE 2: D[m=co][n=x] -> [b][64][OH][320]
// ---------------------------------------------------------------------------
template<int MODE>
__device__ __forceinline__ void conv_phase(
    const _Float16* __restrict__ Xt, const _Float16* __restrict__ Wfl,
    _Float16* __restrict__ OutE, _Float16* __restrict__ OutT,
    const int* rows_top, _Float16* Xs, int NB)
{
    const int t = threadIdx.x;
    const int l = t & 63, w = t >> 6;
    const int i31 = l & 31, h = l >> 5;
    const int wlane = i31 * 16 + h * 8;

    for (int task = blockIdx.x; task < 560; task += NB) {
        const int xt = task % 5;
        const int rem = task / 5;
        const int rg = rem % 28;
        const int b  = rem / 28;
        const bool top = rg >= 24;
        const int trg = rg - 24;
        const int x0 = xt * 64;

        __syncthreads();
        for (int u = t; u < 6 * 66 * 8; u += 256) {
            int row = u / 528;
            int r2  = u - row * 528;
            int x = r2 >> 3, c8 = r2 & 7;
            int grow = top ? ((row < 4) ? rows_top[trg * 4 + row] : -1) : rg * 4 + row;
            int gx = x0 - 1 + x;
            float4 v = make_float4(0.f, 0.f, 0.f, 0.f);
            if ((unsigned)grow < HH && (unsigned)gx < WW)
                v = *(const float4*)&Xt[((size_t)(b * HH + grow) * WW + gx) * 64 + c8 * 8];
            *(float4*)&Xs[(row * 66 + x) * 72 + c8 * 8] = v;
        }
        __syncthreads();

        floatx16 acc[2][2];
#pragma unroll
        for (int a = 0; a < 2; ++a)
#pragma unroll
            for (int c = 0; c < 2; ++c)
                acc[a][c] = (floatx16){0.f,0.f,0.f,0.f, 0.f,0.f,0.f,0.f,
                                       0.f,0.f,0.f,0.f, 0.f,0.f,0.f,0.f};

        const _Float16* xb  = &Xs[(w * 66 + i31) * 72 + h * 8];
        const _Float16* wp0 = Wfl + wlane;
        if (top) conv_core<MODE, 3>(xb, wp0, acc);
        else     conv_core<MODE, 9>(xb, wp0, acc);

        const int OH = top ? 16 : HH;
        const int om = top ? (trg * 4 + w) : (rg * 4 + w);
        _Float16* Out = top ? OutT : OutE;
#pragma unroll
        for (int a = 0; a < 2; ++a)
#pragma unroll
            for (int c = 0; c < 2; ++c)
#pragma unroll
                for (int r = 0; r < 16; ++r) {
                    int dm = (r & 3) + 8 * (r >> 2) + 4 * h;
                    if (MODE == 1) {
                        int x  = x0 + a * 32 + dm;
                        int co = c * 32 + i31;
                        Out[((size_t)(b * OH + om) * WW + x) * 64 + co] = (_Float16)acc[a][c][r];
                    } else {
                        int co = a * 32 + dm;
                        int x  = x0 + c * 32 + i31;
                        Out[((size_t)(b * 64 + co) * OH + om) * WW + x] = (_Float16)acc[a][c][r];
                    }
                }
    }
}

// ---------------------------------------------------------------------------
// Phase 2: blend layer1  (co-contiguous layout), LDS-staged, rolling regs
// ---------------------------------------------------------------------------
__device__ __forceinline__ void blend1_phase(
    const _Float16* __restrict__ Cb, const _Float16* __restrict__ T,
    const float* __restrict__ bias, _Float16* Xt2,
    const ShiftInfo& si, _Float16* sh, int NB)
{
    _Float16* Cs = sh;                 // [96][16][8]
    _Float16* Ts = sh + 96 * 16 * 8;   // [16][16][8]
    const int t = threadIdx.x;
    const half8_t z = {0,0,0,0,0,0,0,0};

    for (int task = blockIdx.x; task < 640; task += NB) {
        const int cg = task & 7;
        const int xt = (task >> 3) % 20;
        const int b  = task / 160;
        const int x0 = xt * 16;

        __syncthreads();
        for (int u = t; u < 96 * 16; u += 256) {
            int row = u >> 4, xl = u & 15;
            *(half8_t*)&Cs[u * 8] =
                *(const half8_t*)&Cb[((size_t)(b * HH + row) * WW + x0 + xl) * 64 + cg * 8];
        }
        for (int u = t; u < 16 * 16; u += 256) {
            int row = u >> 4, xl = u & 15;
            *(half8_t*)&Ts[u * 8] =
                *(const half8_t*)&T[((size_t)(b * 16 + row) * WW + x0 + xl) * 64 + cg * 8];
        }
        __syncthreads();

        const int xl = t & 15, yt = t >> 4;
        half8_t bv;
#pragma unroll
        for (int j = 0; j < 8; ++j) bv[j] = (_Float16)bias[cg * 8 + j];

        const int y0 = yt * 6;
        half8_t cur[NP];
#pragma unroll
        for (int d = 0; d < NP; ++d) {
            int r = y0 + si.s0[d] - 1;
            cur[d] = (r < HH) ? *(const half8_t*)&Cs[(r * 16 + xl) * 8] : z;
        }
        for (int y = y0; y < y0 + 6; ++y) {
            half8_t m = z;
#pragma unroll
            for (int d = 0; d < NP; ++d) {
                int r1 = y + si.s0[d];
                half8_t v1 = (r1 < HH) ? *(const half8_t*)&Cs[(r1 * 16 + xl) * 8] : z;
                half8_t v0 = cur[d];
                cur[d] = v1;
                _Float16 a = (_Float16)si.wa[d], wg = (_Float16)si.wb[d];
                half8_t p;
                if (y == 0) {
                    half8_t t0 = *(const half8_t*)&Ts[((2 * d) * 16 + xl) * 8];
                    half8_t t1 = *(const half8_t*)&Ts[((2 * d + 1) * 16 + xl) * 8];
                    p = a * (v0 - t0) + wg * (v1 - t1);
                } else {
                    p = a * v0 + wg * v1;
                }
                m = (d == 0) ? p : __builtin_elementwise_max(m, p);
            }
            half8_t o = __builtin_elementwise_max(m + bv, z);
            *(half8_t*)&Xt2[((size_t)(b * HH + y) * WW + x0 + xl) * 64 + cg * 8] = o;
        }
    }
}

// ---------------------------------------------------------------------------
// Phase 4: blend layer2 (x-contiguous layout) -> fp32 output
// ---------------------------------------------------------------------------
__device__ __forceinline__ void blend2_phase(
    const _Float16* __restrict__ Cb, const _Float16* __restrict__ T,
    const float* __restrict__ bias, float* Out,
    const ShiftInfo& si, _Float16* sh, int NB)
{
    _Float16* Cs = sh;             // [96][64]
    _Float16* Ts = sh + 96 * 64;   // [16][64]
    const int t = threadIdx.x;
    const half8_t z = {0,0,0,0,0,0,0,0};

    for (int task = blockIdx.x; task < 1280; task += NB) {
        const int xt = task % 5;
        const int rem = task / 5;
        const int co = rem & 63;
        const int b  = rem >> 6;
        const int x0 = xt * 64;

        __syncthreads();
        for (int u = t; u < 96 * 8; u += 256) {
            int row = u >> 3, x8 = u & 7;
            *(half8_t*)&Cs[row * 64 + x8 * 8] =
                *(const half8_t*)&Cb[((size_t)(b * 64 + co) * HH + row) * WW + x0 + x8 * 8];
        }
        for (int u = t; u < 16 * 8; u += 256) {
            int row = u >> 3, x8 = u & 7;
            *(half8_t*)&Ts[row * 64 + x8 * 8] =
                *(const half8_t*)&T[((size_t)(b * 64 + co) * 16 + row) * WW + x0 + x8 * 8];
        }
        __syncthreads();

        const int x8 = t & 7, yt = t >> 3;
        const float bvf = bias[co];
        const int y0 = yt * 3;

        half8_t cur[NP];
#pragma unroll
        for (int d = 0; d < NP; ++d) {
            int r = y0 + si.s0[d] - 1;
            cur[d] = (r < HH) ? *(const half8_t*)&Cs[r * 64 + x8 * 8] : z;
        }
        for (int y = y0; y < y0 + 3; ++y) {
            half8_t m = z;
#pragma unroll
            for (int d = 0; d < NP; ++d) {
                int r1 = y + si.s0[d];
                half8_t v1 = (r1 < HH) ? *(const half8_t*)&Cs[r1 * 64 + x8 * 8] : z;
                half8_t v0 = cur[d];
                cur[d] = v1;
                _Float16 a = (_Float16)si.wa[d], wg = (_Float16)si.wb[d];
                half8_t p;
                if (y == 0) {
                    half8_t t0 = *(const half8_t*)&Ts[(2 * d) * 64 + x8 * 8];
                    half8_t t1 = *(const half8_t*)&Ts[(2 * d + 1) * 64 + x8 * 8];
                    p = a * (v0 - t0) + wg * (v1 - t1);
                } else {
                    p = a * v0 + wg * v1;
                }
                m = (d == 0) ? p : __builtin_elementwise_max(m, p);
            }
            float4 o0, o1;
            o0.x = fmaxf((float)m[0] + bvf, 0.f);
            o0.y = fmaxf((float)m[1] + bvf, 0.f);
            o0.z = fmaxf((float)m[2] + bvf, 0.f);
            o0.w = fmaxf((float)m[3] + bvf, 0.f);
            o1.x = fmaxf((float)m[4] + bvf, 0.f);
            o1.y = fmaxf((float)m[5] + bvf, 0.f);
            o1.z = fmaxf((float)m[6] + bvf, 0.f);
            o1.w = fmaxf((float)m[7] + bvf, 0.f);
            float* op = Out + ((size_t)(b * 64 + co) * HH + y) * WW + x0 + x8 * 8;
            *(float4*)op = o0;
            *(float4*)(op + 4) = o1;
        }
    }
}

// ---------------------------------------------------------------------------
__global__ void __launch_bounds__(256, 2) mega_kernel(
    const float* __restrict__ X, const float* __restrict__ W1,
    const float* __restrict__ b1v, const float* __restrict__ W2,
    const float* __restrict__ b2v,
    _Float16* __restrict__ Xt1, _Float16* __restrict__ Cb,
    _Float16* __restrict__ T, _Float16* __restrict__ Wf,
    _Float16* Xt2, float* Out, ShiftInfo si, int NB)
{
    __shared__ __align__(16) _Float16 sh[6 * 66 * 72];   // 57,024 B (phase union)
    cg::grid_group grid = cg::this_grid();

    prep_phase(X, W1, W2, Xt1, Wf, sh, NB);
    grid.sync();
    conv_phase<1>(Xt1, Wf, Cb, T, si.rows, sh, NB);
    grid.sync();
    blend1_phase(Cb, T, b1v, Xt2, si, sh, NB);
    grid.sync();
    conv_phase<2>(Xt2, Wf + 36864, Cb, T, si.rows, sh, NB);
    grid.sync();
    blend2_phase(Cb, T, b2v, Out, si, sh, NB);
}

// ---------------------------------------------------------------------------
extern "C" void kernel_launch(void* const* d_in, const int* in_sizes, int n_in,
                              void* d_out, int out_size, void* d_ws, size_t ws_size,
                              hipStream_t stream) {
    const float* x  = (const float*)d_in[0];
    const float* W1 = (const float*)d_in[1];
    const float* b1 = (const float*)d_in[2];
    const float* W2 = (const float*)d_in[3];
    const float* b2 = (const float*)d_in[4];
    float* out = (float*)d_out;

    _Float16* Xt1 = (_Float16*)d_ws;            // 7,864,320 halves
    _Float16* Cb  = Xt1 + 7864320;              // 7,864,320
    _Float16* T   = Cb  + 7864320;              // 1,310,720
    _Float16* Wf  = T   + 1310720;              // 73,728 (both layers, MFMA layout)
    _Float16* Xt2 = (_Float16*)d_out;           // f16 scratch inside d_out

    ShiftInfo si;
    for (int d = 0; d < NP; ++d) {
        double disp = 0.02 + d * (0.98 / 7.0);
        double sh   = 76.0 * disp;
        int s0      = (int)floor(sh);
        double w    = sh - (double)s0;
        si.s0[d] = s0;
        si.wa[d] = (float)(1.0 - w);
        si.wb[d] = (float)w;
        si.rows[2 * d]     = s0 - 1;
        si.rows[2 * d + 1] = s0;
    }

    int maxB = 0;
    hipOccupancyMaxActiveBlocksPerMultiprocessor(&maxB, mega_kernel, 256, 0);
    if (maxB < 1) maxB = 1;
    int NB = maxB * 256;
    if (NB > 512) NB = 512;

    void* args[] = { (void*)&x, (void*)&W1, (void*)&b1, (void*)&W2, (void*)&b2,
                     (void*)&Xt1, (void*)&Cb, (void*)&T, (void*)&Wf,
                     (void*)&Xt2, (void*)&out, (void*)&si, (void*)&NB };
    hipLaunchCooperativeKernel(mega_kernel, dim3(NB), dim3(256), args, 0, stream);
}

// Round 5
// 191.287 us; speedup vs baseline: 2.1116x; 2.1116x over previous
//
#include <hip/hip_runtime.h>
#include <math.h>

#define HH 96
#define WW 320
#define NP 8

typedef _Float16 half8_t  __attribute__((ext_vector_type(8)));
typedef _Float16 half4_t  __attribute__((ext_vector_type(4)));
typedef float    floatx16 __attribute__((ext_vector_type(16)));

struct ShiftInfo {
    int   s0[NP];
    float wa[NP];
    float wb[NP];
    int   rows[16];
};

// ---------------------------------------------------------------------------
// prep: blockIdx.x < 384 -> transpose+cvt one (b,y) row of X into Xt f16
//       blockIdx.x >= 384 -> weight cvt to MFMA-fragment-native layout:
//       Wf[layer][pos][mt][ks][i31][h][j] = W[co=mt*32+i31][ci=ks*16+h*8+j][pos]
//       so a wave's fragment load is base + lane*16B (fully coalesced 1KB).
// ---------------------------------------------------------------------------
__global__ __launch_bounds__(256) void prep_kernel(
    const float* __restrict__ X, const float* __restrict__ W1,
    const float* __restrict__ W2, _Float16* __restrict__ Xt,
    _Float16* __restrict__ Wf)
{
    __shared__ __align__(16) _Float16 Ls[64 * 324];
    const int bx = blockIdx.x, t = threadIdx.x;
    if (bx < 384) {
        const int y = bx % HH, b = bx / HH;
        for (int u = t; u < 64 * 80; u += 256) {
            int ci = u / 80;
            int x4 = (u - ci * 80) * 4;
            float4 v = *(const float4*)&X[((size_t)(b * 64 + ci) * HH + y) * WW + x4];
            half4_t hv = { (_Float16)v.x, (_Float16)v.y, (_Float16)v.z, (_Float16)v.w };
            *(half4_t*)&Ls[ci * 324 + x4] = hv;
        }
        __syncthreads();
        const int ci8 = t & 7, xg = t >> 3;
        for (int it = 0; it < 10; ++it) {
            int x = xg + 32 * it;
            half8_t o;
#pragma unroll
            for (int j = 0; j < 8; ++j) o[j] = Ls[(ci8 * 8 + j) * 324 + x];
            *(half8_t*)&Xt[((size_t)(b * HH + y) * WW + x) * 64 + ci8 * 8] = o;
        }
    } else {
        const int k = bx - 384;                  // 0..17
        const int layer = k / 9, pos = k - layer * 9;
        const float* Ws = layer ? W2 : W1;
        _Float16* Wd = Wf + layer * 36864 + pos * 4096;
        for (int u = t; u < 4096; u += 256) {
            int mt  = u >> 11;
            int ks  = (u >> 9) & 3;
            int i31 = (u >> 4) & 31;
            int h   = (u >> 3) & 1;
            int j   = u & 7;
            int co  = mt * 32 + i31;
            int ci  = ks * 16 + h * 8 + j;
            Wd[u] = (_Float16)Ws[((size_t)co * 64 + ci) * 9 + pos];
        }
    }
}

// ---------------------------------------------------------------------------
// conv core: NPOS compile-time (9 = full 3x3, 3 = top 1x3)
// ---------------------------------------------------------------------------
template<int MODE, int NPOS>
__device__ __forceinline__ void conv_core(
    const _Float16* xb, const _Float16* wp0, floatx16 (&acc)[2][2])
{
#pragma unroll
    for (int pos = 0; pos < NPOS; ++pos) {
        const int ky = pos / 3, kx = pos - ky * 3;
        const _Float16* wp = wp0 + pos * 4096;
#pragma unroll
        for (int ks = 0; ks < 4; ++ks) {
            half8_t wfr0 = *(const half8_t*)(wp + ks * 512);
            half8_t wfr1 = *(const half8_t*)(wp + 2048 + ks * 512);
            half8_t xfr0 = *(const half8_t*)(xb + (ky * 66 + kx) * 72 + ks * 16);
            half8_t xfr1 = *(const half8_t*)(xb + (ky * 66 + kx + 32) * 72 + ks * 16);
            if (MODE == 1) {
                acc[0][0] = __builtin_amdgcn_mfma_f32_32x32x16_f16(xfr0, wfr0, acc[0][0], 0, 0, 0);
                acc[0][1] = __builtin_amdgcn_mfma_f32_32x32x16_f16(xfr0, wfr1, acc[0][1], 0, 0, 0);
                acc[1][0] = __builtin_amdgcn_mfma_f32_32x32x16_f16(xfr1, wfr0, acc[1][0], 0, 0, 0);
                acc[1][1] = __builtin_amdgcn_mfma_f32_32x32x16_f16(xfr1, wfr1, acc[1][1], 0, 0, 0);
            } else {
                acc[0][0] = __builtin_amdgcn_mfma_f32_32x32x16_f16(wfr0, xfr0, acc[0][0], 0, 0, 0);
                acc[0][1] = __builtin_amdgcn_mfma_f32_32x32x16_f16(wfr0, xfr1, acc[0][1], 0, 0, 0);
                acc[1][0] = __builtin_amdgcn_mfma_f32_32x32x16_f16(wfr1, xfr0, acc[1][0], 0, 0, 0);
                acc[1][1] = __builtin_amdgcn_mfma_f32_32x32x16_f16(wfr1, xfr1, acc[1][1], 0, 0, 0);
            }
        }
    }
}

// ---------------------------------------------------------------------------
// MFMA implicit-GEMM conv (rg<24: ext rows -> OutE; rg>=24: top rows -> OutT)
// MODE 1: D[m=x][n=co] -> [b][OH][320][64];  MODE 2: D[m=co][n=x] -> [b][64][OH][320]
// grid (5, 28, 4), block 256 (4 waves; wave = one output row)
// ---------------------------------------------------------------------------
template<int MODE>
__global__ __launch_bounds__(256, 2) void conv_kernel(
    const _Float16* __restrict__ Xt, const _Float16* __restrict__ Wfl,
    _Float16* __restrict__ OutE, _Float16* __restrict__ OutT, ShiftInfo si)
{
    __shared__ __align__(16) _Float16 Xs[6 * 66 * 72];
    const int xt = blockIdx.x, rg = blockIdx.y, b = blockIdx.z;
    const bool top = rg >= 24;
    const int trg = rg - 24;
    const int x0 = xt * 64;
    const int t  = threadIdx.x;

    for (int u = t; u < 6 * 66 * 8; u += 256) {
        int row = u / 528;
        int r2  = u - row * 528;
        int x = r2 >> 3, c8 = r2 & 7;
        int grow = top ? ((row < 4) ? si.rows[trg * 4 + row] : -1) : rg * 4 + row;
        int gx = x0 - 1 + x;
        float4 v = make_float4(0.f, 0.f, 0.f, 0.f);
        if ((unsigned)grow < HH && (unsigned)gx < WW)
            v = *(const float4*)&Xt[((size_t)(b * HH + grow) * WW + gx) * 64 + c8 * 8];
        *(float4*)&Xs[(row * 66 + x) * 72 + c8 * 8] = v;
    }
    __syncthreads();

    const int l = t & 63, w = t >> 6;
    const int i31 = l & 31, h = l >> 5;

    floatx16 acc[2][2];
#pragma unroll
    for (int a = 0; a < 2; ++a)
#pragma unroll
        for (int c = 0; c < 2; ++c)
            acc[a][c] = (floatx16){0.f,0.f,0.f,0.f, 0.f,0.f,0.f,0.f,
                                   0.f,0.f,0.f,0.f, 0.f,0.f,0.f,0.f};

    const _Float16* xb  = &Xs[(w * 66 + i31) * 72 + h * 8];
    const _Float16* wp0 = Wfl + i31 * 16 + h * 8;
    if (top) conv_core<MODE, 3>(xb, wp0, acc);
    else     conv_core<MODE, 9>(xb, wp0, acc);

    const int OH = top ? 16 : HH;
    const int om = top ? (trg * 4 + w) : (rg * 4 + w);
    _Float16* Out = top ? OutT : OutE;
#pragma unroll
    for (int a = 0; a < 2; ++a)
#pragma unroll
        for (int c = 0; c < 2; ++c)
#pragma unroll
            for (int r = 0; r < 16; ++r) {
                int dm = (r & 3) + 8 * (r >> 2) + 4 * h;
                if (MODE == 1) {
                    int x  = x0 + a * 32 + dm;
                    int co = c * 32 + i31;
                    Out[((size_t)(b * OH + om) * WW + x) * 64 + co] = (_Float16)acc[a][c][r];
                } else {
                    int co = a * 32 + dm;
                    int x  = x0 + c * 32 + i31;
                    Out[((size_t)(b * 64 + co) * OH + om) * WW + x] = (_Float16)acc[a][c][r];
                }
            }
}

// ---------------------------------------------------------------------------
// blend1: C[b][96][320][64] + T[b][16][320][64] -> Xt2[b][96][320][64] (f16)
// LDS-staged (each C element read once from global). grid 640, block 256.
// task = (cg 8) x (xt 20) x (b 4); x0 = xt*16, co-group cg*8.
// ---------------------------------------------------------------------------
__global__ __launch_bounds__(256) void blend1_kernel(
    const _Float16* __restrict__ Cb, const _Float16* __restrict__ T,
    const float* __restrict__ bias, _Float16* __restrict__ Xt2, ShiftInfo si)
{
    __shared__ __align__(16) _Float16 Cs[96 * 16 * 8];
    __shared__ __align__(16) _Float16 Ts[16 * 16 * 8];
    const int task = blockIdx.x, t = threadIdx.x;
    const int cg = task & 7;
    const int xt = (task >> 3) % 20;
    const int b  = task / 160;
    const int x0 = xt * 16;
    const half8_t z = {0,0,0,0,0,0,0,0};

    for (int u = t; u < 96 * 16; u += 256) {
        int row = u >> 4, xl = u & 15;
        *(half8_t*)&Cs[u * 8] =
            *(const half8_t*)&Cb[((size_t)(b * HH + row) * WW + x0 + xl) * 64 + cg * 8];
    }
    for (int u = t; u < 16 * 16; u += 256) {
        int row = u >> 4, xl = u & 15;
        *(half8_t*)&Ts[u * 8] =
            *(const half8_t*)&T[((size_t)(b * 16 + row) * WW + x0 + xl) * 64 + cg * 8];
    }
    __syncthreads();

    const int xl = t & 15, yt = t >> 4;
    half8_t bv;
#pragma unroll
    for (int j = 0; j < 8; ++j) bv[j] = (_Float16)bias[cg * 8 + j];

    const int y0 = yt * 6;
    half8_t cur[NP];
#pragma unroll
    for (int d = 0; d < NP; ++d) {
        int r = y0 + si.s0[d] - 1;
        cur[d] = (r < HH) ? *(const half8_t*)&Cs[(r * 16 + xl) * 8] : z;
    }
    for (int y = y0; y < y0 + 6; ++y) {
        half8_t m = z;
#pragma unroll
        for (int d = 0; d < NP; ++d) {
            int r1 = y + si.s0[d];
            half8_t v1 = (r1 < HH) ? *(const half8_t*)&Cs[(r1 * 16 + xl) * 8] : z;
            half8_t v0 = cur[d];
            cur[d] = v1;
            _Float16 a = (_Float16)si.wa[d], wg = (_Float16)si.wb[d];
            half8_t p;
            if (y == 0) {
                half8_t t0 = *(const half8_t*)&Ts[((2 * d) * 16 + xl) * 8];
                half8_t t1 = *(const half8_t*)&Ts[((2 * d + 1) * 16 + xl) * 8];
                p = a * (v0 - t0) + wg * (v1 - t1);
            } else {
                p = a * v0 + wg * v1;
            }
            m = (d == 0) ? p : __builtin_elementwise_max(m, p);
        }
        half8_t o = __builtin_elementwise_max(m + bv, z);
        *(half8_t*)&Xt2[((size_t)(b * HH + y) * WW + x0 + xl) * 64 + cg * 8] = o;
    }
}

// ---------------------------------------------------------------------------
// blend2: C[b][64][96][320] + T[b][64][16][320] -> Out fp32 [b][64][96][320]
// grid 1280 = (xt 5) x (co 64) x (b 4), block 256.
// ---------------------------------------------------------------------------
__global__ __launch_bounds__(256) void blend2_kernel(
    const _Float16* __restrict__ Cb, const _Float16* __restrict__ T,
    const float* __restrict__ bias, float* __restrict__ Out, ShiftInfo si)
{
    __shared__ __align__(16) _Float16 Cs[96 * 64];
    __shared__ __align__(16) _Float16 Ts[16 * 64];
    const int task = blockIdx.x, t = threadIdx.x;
    const int xt = task % 5;
    const int rem = task / 5;
    const int co = rem & 63;
    const int b  = rem >> 6;
    const int x0 = xt * 64;
    const half8_t z = {0,0,0,0,0,0,0,0};

    for (int u = t; u < 96 * 8; u += 256) {
        int row = u >> 3, x8 = u & 7;
        *(half8_t*)&Cs[row * 64 + x8 * 8] =
            *(const half8_t*)&Cb[((size_t)(b * 64 + co) * HH + row) * WW + x0 + x8 * 8];
    }
    for (int u = t; u < 16 * 8; u += 256) {
        int row = u >> 3, x8 = u & 7;
        *(half8_t*)&Ts[row * 64 + x8 * 8] =
            *(const half8_t*)&T[((size_t)(b * 64 + co) * 16 + row) * WW + x0 + x8 * 8];
    }
    __syncthreads();

    const int x8 = t & 7, yt = t >> 3;
    const float bvf = bias[co];
    const int y0 = yt * 3;

    half8_t cur[NP];
#pragma unroll
    for (int d = 0; d < NP; ++d) {
        int r = y0 + si.s0[d] - 1;
        cur[d] = (r < HH) ? *(const half8_t*)&Cs[r * 64 + x8 * 8] : z;
    }
    for (int y = y0; y < y0 + 3; ++y) {
        half8_t m = z;
#pragma unroll
        for (int d = 0; d < NP; ++d) {
            int r1 = y + si.s0[d];
            half8_t v1 = (r1 < HH) ? *(const half8_t*)&Cs[r1 * 64 + x8 * 8] : z;
            half8_t v0 = cur[d];
            cur[d] = v1;
            _Float16 a = (_Float16)si.wa[d], wg = (_Float16)si.wb[d];
            half8_t p;
            if (y == 0) {
                half8_t t0 = *(const half8_t*)&Ts[(2 * d) * 64 + x8 * 8];
                half8_t t1 = *(const half8_t*)&Ts[(2 * d + 1) * 64 + x8 * 8];
                p = a * (v0 - t0) + wg * (v1 - t1);
            } else {
                p = a * v0 + wg * v1;
            }
            m = (d == 0) ? p : __builtin_elementwise_max(m, p);
        }
        float4 o0, o1;
        o0.x = fmaxf((float)m[0] + bvf, 0.f);
        o0.y = fmaxf((float)m[1] + bvf, 0.f);
        o0.z = fmaxf((float)m[2] + bvf, 0.f);
        o0.w = fmaxf((float)m[3] + bvf, 0.f);
        o1.x = fmaxf((float)m[4] + bvf, 0.f);
        o1.y = fmaxf((float)m[5] + bvf, 0.f);
        o1.z = fmaxf((float)m[6] + bvf, 0.f);
        o1.w = fmaxf((float)m[7] + bvf, 0.f);
        float* op = Out + ((size_t)(b * 64 + co) * HH + y) * WW + x0 + x8 * 8;
        *(float4*)op = o0;
        *(float4*)(op + 4) = o1;
    }
}

// ---------------------------------------------------------------------------
extern "C" void kernel_launch(void* const* d_in, const int* in_sizes, int n_in,
                              void* d_out, int out_size, void* d_ws, size_t ws_size,
                              hipStream_t stream) {
    const float* x  = (const float*)d_in[0];
    const float* W1 = (const float*)d_in[1];
    const float* b1 = (const float*)d_in[2];
    const float* W2 = (const float*)d_in[3];
    const float* b2 = (const float*)d_in[4];
    float* out = (float*)d_out;

    _Float16* Xt1 = (_Float16*)d_ws;            // 7,864,320 halves
    _Float16* Cb  = Xt1 + 7864320;              // 7,864,320
    _Float16* T   = Cb  + 7864320;              // 1,310,720
    _Float16* Wf  = T   + 1310720;              // 73,728 (both layers, MFMA layout)
    _Float16* Xt2 = (_Float16*)d_out;           // f16 scratch inside d_out

    ShiftInfo si;
    for (int d = 0; d < NP; ++d) {
        double disp = 0.02 + d * (0.98 / 7.0);
        double sh   = 76.0 * disp;
        int s0      = (int)floor(sh);
        double w    = sh - (double)s0;
        si.s0[d] = s0;
        si.wa[d] = (float)(1.0 - w);
        si.wb[d] = (float)w;
        si.rows[2 * d]     = s0 - 1;
        si.rows[2 * d + 1] = s0;
    }

    prep_kernel<<<dim3(402), 256, 0, stream>>>(x, W1, W2, Xt1, Wf);

    conv_kernel<1><<<dim3(5, 28, 4), 256, 0, stream>>>(Xt1, Wf, Cb, T, si);
    blend1_kernel<<<dim3(640), 256, 0, stream>>>(Cb, T, b1, Xt2, si);

    conv_kernel<2><<<dim3(5, 28, 4), 256, 0, stream>>>(Xt2, Wf + 36864, Cb, T, si);
    blend2_kernel<<<dim3(1280), 256, 0, stream>>>(Cb, T, b2, out, si);
}

// Round 6
// 181.751 us; speedup vs baseline: 2.2224x; 1.0525x over previous
//
#include <hip/hip_runtime.h>
#include <math.h>

#define HH 96
#define WW 320
#define NP 8

typedef _Float16 half8_t  __attribute__((ext_vector_type(8)));
typedef _Float16 half4_t  __attribute__((ext_vector_type(4)));
typedef float    floatx16 __attribute__((ext_vector_type(16)));

struct ShiftInfo {
    int   s0[NP];
    float wa[NP];
    float wb[NP];
    int   rows[16];
};

// ---------------------------------------------------------------------------
// prep: blockIdx.x < 384 -> transpose+cvt one (b,y) row of X into Xt f16
//       blockIdx.x >= 384 -> weight cvt to MFMA-fragment-native layout:
//       Wf[layer][pos][mt][ks][i31][h][j] = W[co=mt*32+i31][ci=ks*16+h*8+j][pos]
//       so a wave's fragment load is base + lane*16B (fully coalesced 1KB).
// ---------------------------------------------------------------------------
__global__ __launch_bounds__(256) void prep_kernel(
    const float* __restrict__ X, const float* __restrict__ W1,
    const float* __restrict__ W2, _Float16* __restrict__ Xt,
    _Float16* __restrict__ Wf)
{
    __shared__ __align__(16) _Float16 Ls[64 * 324];
    const int bx = blockIdx.x, t = threadIdx.x;
    if (bx < 384) {
        const int y = bx % HH, b = bx / HH;
        for (int u = t; u < 64 * 80; u += 256) {
            int ci = u / 80;
            int x4 = (u - ci * 80) * 4;
            float4 v = *(const float4*)&X[((size_t)(b * 64 + ci) * HH + y) * WW + x4];
            half4_t hv = { (_Float16)v.x, (_Float16)v.y, (_Float16)v.z, (_Float16)v.w };
            *(half4_t*)&Ls[ci * 324 + x4] = hv;
        }
        __syncthreads();
        const int ci8 = t & 7, xg = t >> 3;
        for (int it = 0; it < 10; ++it) {
            int x = xg + 32 * it;
            half8_t o;
#pragma unroll
            for (int j = 0; j < 8; ++j) o[j] = Ls[(ci8 * 8 + j) * 324 + x];
            *(half8_t*)&Xt[((size_t)(b * HH + y) * WW + x) * 64 + ci8 * 8] = o;
        }
    } else {
        const int k = bx - 384;                  // 0..17
        const int layer = k / 9, pos = k - layer * 9;
        const float* Ws = layer ? W2 : W1;
        _Float16* Wd = Wf + layer * 36864 + pos * 4096;
        for (int u = t; u < 4096; u += 256) {
            int mt  = u >> 11;
            int ks  = (u >> 9) & 3;
            int i31 = (u >> 4) & 31;
            int h   = (u >> 3) & 1;
            int j   = u & 7;
            int co  = mt * 32 + i31;
            int ci  = ks * 16 + h * 8 + j;
            Wd[u] = (_Float16)Ws[((size_t)co * 64 + ci) * 9 + pos];
        }
    }
}

// ---------------------------------------------------------------------------
// conv core: NPOS compile-time (9 = full 3x3, 3 = top 1x3)
// ---------------------------------------------------------------------------
template<int MODE, int NPOS>
__device__ __forceinline__ void conv_core(
    const _Float16* xb, const _Float16* wp0, floatx16 (&acc)[2][2])
{
#pragma unroll
    for (int pos = 0; pos < NPOS; ++pos) {
        const int ky = pos / 3, kx = pos - ky * 3;
        const _Float16* wp = wp0 + pos * 4096;
#pragma unroll
        for (int ks = 0; ks < 4; ++ks) {
            half8_t wfr0 = *(const half8_t*)(wp + ks * 512);
            half8_t wfr1 = *(const half8_t*)(wp + 2048 + ks * 512);
            half8_t xfr0 = *(const half8_t*)(xb + (ky * 66 + kx) * 72 + ks * 16);
            half8_t xfr1 = *(const half8_t*)(xb + (ky * 66 + kx + 32) * 72 + ks * 16);
            if (MODE == 1) {
                acc[0][0] = __builtin_amdgcn_mfma_f32_32x32x16_f16(xfr0, wfr0, acc[0][0], 0, 0, 0);
                acc[0][1] = __builtin_amdgcn_mfma_f32_32x32x16_f16(xfr0, wfr1, acc[0][1], 0, 0, 0);
                acc[1][0] = __builtin_amdgcn_mfma_f32_32x32x16_f16(xfr1, wfr0, acc[1][0], 0, 0, 0);
                acc[1][1] = __builtin_amdgcn_mfma_f32_32x32x16_f16(xfr1, wfr1, acc[1][1], 0, 0, 0);
            } else {
                acc[0][0] = __builtin_amdgcn_mfma_f32_32x32x16_f16(wfr0, xfr0, acc[0][0], 0, 0, 0);
                acc[0][1] = __builtin_amdgcn_mfma_f32_32x32x16_f16(wfr0, xfr1, acc[0][1], 0, 0, 0);
                acc[1][0] = __builtin_amdgcn_mfma_f32_32x32x16_f16(wfr1, xfr0, acc[1][0], 0, 0, 0);
                acc[1][1] = __builtin_amdgcn_mfma_f32_32x32x16_f16(wfr1, xfr1, acc[1][1], 0, 0, 0);
            }
        }
    }
}

// ---------------------------------------------------------------------------
// MFMA implicit-GEMM conv (rg<24: ext rows -> OutE; rg>=24: top rows -> OutT)
// MODE 1: D[m=x][n=co] -> [b][OH][320][64];  MODE 2: D[m=co][n=x] -> [b][64][OH][320]
// grid (5, 28, 4), block 256 (4 waves; wave = one output row)
// ---------------------------------------------------------------------------
template<int MODE>
__global__ __launch_bounds__(256, 2) void conv_kernel(
    const _Float16* __restrict__ Xt, const _Float16* __restrict__ Wfl,
    _Float16* __restrict__ OutE, _Float16* __restrict__ OutT, ShiftInfo si)
{
    __shared__ __align__(16) _Float16 Xs[6 * 66 * 72];
    const int xt = blockIdx.x, rg = blockIdx.y, b = blockIdx.z;
    const bool top = rg >= 24;
    const int trg = rg - 24;
    const int x0 = xt * 64;
    const int t  = threadIdx.x;

    for (int u = t; u < 6 * 66 * 8; u += 256) {
        int row = u / 528;
        int r2  = u - row * 528;
        int x = r2 >> 3, c8 = r2 & 7;
        int grow = top ? ((row < 4) ? si.rows[trg * 4 + row] : -1) : rg * 4 + row;
        int gx = x0 - 1 + x;
        float4 v = make_float4(0.f, 0.f, 0.f, 0.f);
        if ((unsigned)grow < HH && (unsigned)gx < WW)
            v = *(const float4*)&Xt[((size_t)(b * HH + grow) * WW + gx) * 64 + c8 * 8];
        *(float4*)&Xs[(row * 66 + x) * 72 + c8 * 8] = v;
    }
    __syncthreads();

    const int l = t & 63, w = t >> 6;
    const int i31 = l & 31, h = l >> 5;

    floatx16 acc[2][2];
#pragma unroll
    for (int a = 0; a < 2; ++a)
#pragma unroll
        for (int c = 0; c < 2; ++c)
            acc[a][c] = (floatx16){0.f,0.f,0.f,0.f, 0.f,0.f,0.f,0.f,
                                   0.f,0.f,0.f,0.f, 0.f,0.f,0.f,0.f};

    const _Float16* xb  = &Xs[(w * 66 + i31) * 72 + h * 8];
    const _Float16* wp0 = Wfl + i31 * 16 + h * 8;
    if (top) conv_core<MODE, 3>(xb, wp0, acc);
    else     conv_core<MODE, 9>(xb, wp0, acc);

    const int OH = top ? 16 : HH;
    const int om = top ? (trg * 4 + w) : (rg * 4 + w);
    _Float16* Out = top ? OutT : OutE;
#pragma unroll
    for (int a = 0; a < 2; ++a)
#pragma unroll
        for (int c = 0; c < 2; ++c)
#pragma unroll
            for (int r = 0; r < 16; ++r) {
                int dm = (r & 3) + 8 * (r >> 2) + 4 * h;
                if (MODE == 1) {
                    int x  = x0 + a * 32 + dm;
                    int co = c * 32 + i31;
                    Out[((size_t)(b * OH + om) * WW + x) * 64 + co] = (_Float16)acc[a][c][r];
                } else {
                    int co = a * 32 + dm;
                    int x  = x0 + c * 32 + i31;
                    Out[((size_t)(b * 64 + co) * OH + om) * WW + x] = (_Float16)acc[a][c][r];
                }
            }
}

// ---------------------------------------------------------------------------
// blend1: C[b][96][320][64] + T[b][16][320][64] -> Xt2[b][96][320][64] (f16)
// Full-cache-line blocks: one block = ALL 64 co x 4 x x all 96 y, so every
// global load/store is a full 128-B line (fixes the 4x over-fetch seen in R5).
// grid (80 xt, 4 b), block 256 = 8 co8 x 4 xl x 8 yt. LDS 57 KB.
// ---------------------------------------------------------------------------
__global__ __launch_bounds__(256) void blend1_kernel(
    const _Float16* __restrict__ Cb, const _Float16* __restrict__ T,
    const float* __restrict__ bias, _Float16* __restrict__ Xt2, ShiftInfo si)
{
    __shared__ __align__(16) _Float16 Cs[96 * 4 * 64];   // [row][xl][co] 49 KB
    __shared__ __align__(16) _Float16 Ts[16 * 4 * 64];   // 8 KB
    const int xt = blockIdx.x, b = blockIdx.y, t = threadIdx.x;
    const int x0 = xt * 4;
    const half8_t z = {0,0,0,0,0,0,0,0};

    // stage: contiguous 512 B per row (4 x * 64 co), full-line utilization
    for (int u = t; u < 96 * 32; u += 256) {
        int row = u >> 5, v = u & 31;        // v = xl*8 + c8
        *(half8_t*)&Cs[(row * 32 + v) * 8] =
            *(const half8_t*)&Cb[((size_t)(b * HH + row) * WW + x0 + (v >> 3)) * 64 + (v & 7) * 8];
    }
    for (int u = t; u < 16 * 32; u += 256) {
        int row = u >> 5, v = u & 31;
        *(half8_t*)&Ts[(row * 32 + v) * 8] =
            *(const half8_t*)&T[((size_t)(b * 16 + row) * WW + x0 + (v >> 3)) * 64 + (v & 7) * 8];
    }
    __syncthreads();

    const int co8 = t & 7, xl = (t >> 3) & 3, yt = t >> 5;
    half8_t bv;
#pragma unroll
    for (int j = 0; j < 8; ++j) bv[j] = (_Float16)bias[co8 * 8 + j];

    const int y0 = yt * 12;
    half8_t cur[NP];
#pragma unroll
    for (int d = 0; d < NP; ++d) {
        int r = y0 + si.s0[d] - 1;
        cur[d] = (r < HH) ? *(const half8_t*)&Cs[((r * 4 + xl) * 64) + co8 * 8] : z;
    }
    for (int y = y0; y < y0 + 12; ++y) {
        half8_t m = z;
#pragma unroll
        for (int d = 0; d < NP; ++d) {
            int r1 = y + si.s0[d];
            half8_t v1 = (r1 < HH) ? *(const half8_t*)&Cs[((r1 * 4 + xl) * 64) + co8 * 8] : z;
            half8_t v0 = cur[d];
            cur[d] = v1;
            _Float16 a = (_Float16)si.wa[d], wg = (_Float16)si.wb[d];
            half8_t p;
            if (y == 0) {
                half8_t t0 = *(const half8_t*)&Ts[(((2 * d) * 4 + xl) * 64) + co8 * 8];
                half8_t t1 = *(const half8_t*)&Ts[(((2 * d + 1) * 4 + xl) * 64) + co8 * 8];
                p = a * (v0 - t0) + wg * (v1 - t1);
            } else {
                p = a * v0 + wg * v1;
            }
            m = (d == 0) ? p : __builtin_elementwise_max(m, p);
        }
        half8_t o = __builtin_elementwise_max(m + bv, z);
        *(half8_t*)&Xt2[((size_t)(b * HH + y) * WW + x0 + xl) * 64 + co8 * 8] = o;
    }
}

// ---------------------------------------------------------------------------
// blend2: C[b][64][96][320] + T[b][64][16][320] -> Out fp32 [b][64][96][320]
// grid 1280 = (xt 5) x (co 64) x (b 4), block 256.
// ---------------------------------------------------------------------------
__global__ __launch_bounds__(256) void blend2_kernel(
    const _Float16* __restrict__ Cb, const _Float16* __restrict__ T,
    const float* __restrict__ bias, float* __restrict__ Out, ShiftInfo si)
{
    __shared__ __align__(16) _Float16 Cs[96 * 64];
    __shared__ __align__(16) _Float16 Ts[16 * 64];
    const int task = blockIdx.x, t = threadIdx.x;
    const int xt = task % 5;
    const int rem = task / 5;
    const int co = rem & 63;
    const int b  = rem >> 6;
    const int x0 = xt * 64;
    const half8_t z = {0,0,0,0,0,0,0,0};

    for (int u = t; u < 96 * 8; u += 256) {
        int row = u >> 3, x8 = u & 7;
        *(half8_t*)&Cs[row * 64 + x8 * 8] =
            *(const half8_t*)&Cb[((size_t)(b * 64 + co) * HH + row) * WW + x0 + x8 * 8];
    }
    for (int u = t; u < 16 * 8; u += 256) {
        int row = u >> 3, x8 = u & 7;
        *(half8_t*)&Ts[row * 64 + x8 * 8] =
            *(const half8_t*)&T[((size_t)(b * 64 + co) * 16 + row) * WW + x0 + x8 * 8];
    }
    __syncthreads();

    const int x8 = t & 7, yt = t >> 3;
    const float bvf = bias[co];
    const int y0 = yt * 3;

    half8_t cur[NP];
#pragma unroll
    for (int d = 0; d < NP; ++d) {
        int r = y0 + si.s0[d] - 1;
        cur[d] = (r < HH) ? *(const half8_t*)&Cs[r * 64 + x8 * 8] : z;
    }
    for (int y = y0; y < y0 + 3; ++y) {
        half8_t m = z;
#pragma unroll
        for (int d = 0; d < NP; ++d) {
            int r1 = y + si.s0[d];
            half8_t v1 = (r1 < HH) ? *(const half8_t*)&Cs[r1 * 64 + x8 * 8] : z;
            half8_t v0 = cur[d];
            cur[d] = v1;
            _Float16 a = (_Float16)si.wa[d], wg = (_Float16)si.wb[d];
            half8_t p;
            if (y == 0) {
                half8_t t0 = *(const half8_t*)&Ts[(2 * d) * 64 + x8 * 8];
                half8_t t1 = *(const half8_t*)&Ts[(2 * d + 1) * 64 + x8 * 8];
                p = a * (v0 - t0) + wg * (v1 - t1);
            } else {
                p = a * v0 + wg * v1;
            }
            m = (d == 0) ? p : __builtin_elementwise_max(m, p);
        }
        float4 o0, o1;
        o0.x = fmaxf((float)m[0] + bvf, 0.f);
        o0.y = fmaxf((float)m[1] + bvf, 0.f);
        o0.z = fmaxf((float)m[2] + bvf, 0.f);
        o0.w = fmaxf((float)m[3] + bvf, 0.f);
        o1.x = fmaxf((float)m[4] + bvf, 0.f);
        o1.y = fmaxf((float)m[5] + bvf, 0.f);
        o1.z = fmaxf((float)m[6] + bvf, 0.f);
        o1.w = fmaxf((float)m[7] + bvf, 0.f);
        float* op = Out + ((size_t)(b * 64 + co) * HH + y) * WW + x0 + x8 * 8;
        *(float4*)op = o0;
        *(float4*)(op + 4) = o1;
    }
}

// ---------------------------------------------------------------------------
extern "C" void kernel_launch(void* const* d_in, const int* in_sizes, int n_in,
                              void* d_out, int out_size, void* d_ws, size_t ws_size,
                              hipStream_t stream) {
    const float* x  = (const float*)d_in[0];
    const float* W1 = (const float*)d_in[1];
    const float* b1 = (const float*)d_in[2];
    const float* W2 = (const float*)d_in[3];
    const float* b2 = (const float*)d_in[4];
    float* out = (float*)d_out;

    _Float16* Xt1 = (_Float16*)d_ws;            // 7,864,320 halves
    _Float16* Cb  = Xt1 + 7864320;              // 7,864,320
    _Float16* T   = Cb  + 7864320;              // 1,310,720
    _Float16* Wf  = T   + 1310720;              // 73,728 (both layers, MFMA layout)
    _Float16* Xt2 = (_Float16*)d_out;           // f16 scratch inside d_out

    ShiftInfo si;
    for (int d = 0; d < NP; ++d) {
        double disp = 0.02 + d * (0.98 / 7.0);
        double sh   = 76.0 * disp;
        int s0      = (int)floor(sh);
        double w    = sh - (double)s0;
        si.s0[d] = s0;
        si.wa[d] = (float)(1.0 - w);
        si.wb[d] = (float)w;
        si.rows[2 * d]     = s0 - 1;
        si.rows[2 * d + 1] = s0;
    }

    prep_kernel<<<dim3(402), 256, 0, stream>>>(x, W1, W2, Xt1, Wf);

    conv_kernel<1><<<dim3(5, 28, 4), 256, 0, stream>>>(Xt1, Wf, Cb, T, si);
    blend1_kernel<<<dim3(80, 4), 256, 0, stream>>>(Cb, T, b1, Xt2, si);

    conv_kernel<2><<<dim3(5, 28, 4), 256, 0, stream>>>(Xt2, Wf + 36864, Cb, T, si);
    blend2_kernel<<<dim3(1280), 256, 0, stream>>>(Cb, T, b2, out, si);
}

// Round 7
// 176.406 us; speedup vs baseline: 2.2897x; 1.0303x over previous
//
#include <hip/hip_runtime.h>
#include <math.h>

#define HH 96
#define WW 320
#define NP 8

typedef _Float16 half8_t  __attribute__((ext_vector_type(8)));
typedef _Float16 half4_t  __attribute__((ext_vector_type(4)));
typedef float    floatx16 __attribute__((ext_vector_type(16)));

struct ShiftInfo {
    int   s0[NP];
    float wa[NP];
    float wb[NP];
    int   rows[16];
};

// ---------------------------------------------------------------------------
// prep: blockIdx.x < 384 -> transpose+cvt one (b,y) row of X into Xt f16
//       blockIdx.x >= 384 -> weight cvt to MFMA-fragment-native layout.
//       Ls stride 325 (not 324): gather lane stride 16*650 B = 80 mod 128
//       -> 8 distinct bank slots -> conflict-free transpose gather.
// ---------------------------------------------------------------------------
__global__ __launch_bounds__(256) void prep_kernel(
    const float* __restrict__ X, const float* __restrict__ W1,
    const float* __restrict__ W2, _Float16* __restrict__ Xt,
    _Float16* __restrict__ Wf)
{
    __shared__ __align__(16) _Float16 Ls[64 * 325];
    const int bx = blockIdx.x, t = threadIdx.x;
    if (bx < 384) {
        const int y = bx % HH, b = bx / HH;
        for (int u = t; u < 64 * 80; u += 256) {
            int ci = u / 80;
            int x4 = (u - ci * 80) * 4;
            float4 v = *(const float4*)&X[((size_t)(b * 64 + ci) * HH + y) * WW + x4];
            half4_t hv = { (_Float16)v.x, (_Float16)v.y, (_Float16)v.z, (_Float16)v.w };
            *(half4_t*)&Ls[ci * 325 + x4] = hv;
        }
        __syncthreads();
        const int ci8 = t & 7, xg = t >> 3;
        for (int it = 0; it < 10; ++it) {
            int x = xg + 32 * it;
            half8_t o;
#pragma unroll
            for (int j = 0; j < 8; ++j) o[j] = Ls[(ci8 * 8 + j) * 325 + x];
            *(half8_t*)&Xt[((size_t)(b * HH + y) * WW + x) * 64 + ci8 * 8] = o;
        }
    } else {
        const int k = bx - 384;                  // 0..17
        const int layer = k / 9, pos = k - layer * 9;
        const float* Ws = layer ? W2 : W1;
        _Float16* Wd = Wf + layer * 36864 + pos * 4096;
        for (int u = t; u < 4096; u += 256) {
            int mt  = u >> 11;
            int ks  = (u >> 9) & 3;
            int i31 = (u >> 4) & 31;
            int h   = (u >> 3) & 1;
            int j   = u & 7;
            int co  = mt * 32 + i31;
            int ci  = ks * 16 + h * 8 + j;
            Wd[u] = (_Float16)Ws[((size_t)co * 64 + ci) * 9 + pos];
        }
    }
}

// ---------------------------------------------------------------------------
// conv core with depth-4 software-pipelined fragment loads (register ring).
// Loads for iteration i+3 issue before the MFMAs of iteration i, covering
// ~200-300 cyc L2/LDS latency with ~3 iterations of MFMA issue.
// ---------------------------------------------------------------------------
template<int MODE, int NPOS>
__device__ __forceinline__ void conv_core(
    const _Float16* xb, const _Float16* wp0, floatx16 (&acc)[2][2])
{
    constexpr int NI = NPOS * 4;
    half8_t fw0[4], fw1[4], fx0[4], fx1[4];

    auto ld = [&](int idx, int s) {
        const int pos = idx >> 2, ks = idx & 3;
        const int ky = pos / 3, kx = pos - ky * 3;
        const _Float16* wp = wp0 + pos * 4096 + ks * 512;
        fw0[s] = *(const half8_t*)(wp);
        fw1[s] = *(const half8_t*)(wp + 2048);
        const _Float16* xp = xb + (ky * 66 + kx) * 72 + ks * 16;
        fx0[s] = *(const half8_t*)(xp);
        fx1[s] = *(const half8_t*)(xp + 32 * 72);
    };

#pragma unroll
    for (int s = 0; s < 3; ++s) ld(s, s);

#pragma unroll
    for (int i = 0; i < NI; ++i) {
        if (i + 3 < NI) ld(i + 3, (i + 3) & 3);
        const int s = i & 3;
        if (MODE == 1) {
            acc[0][0] = __builtin_amdgcn_mfma_f32_32x32x16_f16(fx0[s], fw0[s], acc[0][0], 0, 0, 0);
            acc[0][1] = __builtin_amdgcn_mfma_f32_32x32x16_f16(fx0[s], fw1[s], acc[0][1], 0, 0, 0);
            acc[1][0] = __builtin_amdgcn_mfma_f32_32x32x16_f16(fx1[s], fw0[s], acc[1][0], 0, 0, 0);
            acc[1][1] = __builtin_amdgcn_mfma_f32_32x32x16_f16(fx1[s], fw1[s], acc[1][1], 0, 0, 0);
        } else {
            acc[0][0] = __builtin_amdgcn_mfma_f32_32x32x16_f16(fw0[s], fx0[s], acc[0][0], 0, 0, 0);
            acc[0][1] = __builtin_amdgcn_mfma_f32_32x32x16_f16(fw0[s], fx1[s], acc[0][1], 0, 0, 0);
            acc[1][0] = __builtin_amdgcn_mfma_f32_32x32x16_f16(fw1[s], fx0[s], acc[1][0], 0, 0, 0);
            acc[1][1] = __builtin_amdgcn_mfma_f32_32x32x16_f16(fw1[s], fx1[s], acc[1][1], 0, 0, 0);
        }
    }
}

// ---------------------------------------------------------------------------
// MFMA implicit-GEMM conv (rg<24: ext rows -> OutE; rg>=24: top rows -> OutT)
// MODE 1: D[m=x][n=co] -> [b][OH][320][64];  MODE 2: D[m=co][n=x] -> [b][64][OH][320]
// grid (5, 28, 4), block 256 (4 waves; wave = one output row)
// ---------------------------------------------------------------------------
template<int MODE>
__global__ __launch_bounds__(256, 2) void conv_kernel(
    const _Float16* __restrict__ Xt, const _Float16* __restrict__ Wfl,
    _Float16* __restrict__ OutE, _Float16* __restrict__ OutT, ShiftInfo si)
{
    __shared__ __align__(16) _Float16 Xs[6 * 66 * 72];
    const int xt = blockIdx.x, rg = blockIdx.y, b = blockIdx.z;
    const bool top = rg >= 24;
    const int trg = rg - 24;
    const int x0 = xt * 64;
    const int t  = threadIdx.x;

    for (int u = t; u < 6 * 66 * 8; u += 256) {
        int row = u / 528;
        int r2  = u - row * 528;
        int x = r2 >> 3, c8 = r2 & 7;
        int grow = top ? ((row < 4) ? si.rows[trg * 4 + row] : -1) : rg * 4 + row;
        int gx = x0 - 1 + x;
        float4 v = make_float4(0.f, 0.f, 0.f, 0.f);
        if ((unsigned)grow < HH && (unsigned)gx < WW)
            v = *(const float4*)&Xt[((size_t)(b * HH + grow) * WW + gx) * 64 + c8 * 8];
        *(float4*)&Xs[(row * 66 + x) * 72 + c8 * 8] = v;
    }
    __syncthreads();

    const int l = t & 63, w = t >> 6;
    const int i31 = l & 31, h = l >> 5;

    floatx16 acc[2][2];
#pragma unroll
    for (int a = 0; a < 2; ++a)
#pragma unroll
        for (int c = 0; c < 2; ++c)
            acc[a][c] = (floatx16){0.f,0.f,0.f,0.f, 0.f,0.f,0.f,0.f,
                                   0.f,0.f,0.f,0.f, 0.f,0.f,0.f,0.f};

    const _Float16* xb  = &Xs[(w * 66 + i31) * 72 + h * 8];
    const _Float16* wp0 = Wfl + i31 * 16 + h * 8;
    if (top) conv_core<MODE, 3>(xb, wp0, acc);
    else     conv_core<MODE, 9>(xb, wp0, acc);

    const int OH = top ? 16 : HH;
    const int om = top ? (trg * 4 + w) : (rg * 4 + w);
    _Float16* Out = top ? OutT : OutE;
#pragma unroll
    for (int a = 0; a < 2; ++a)
#pragma unroll
        for (int c = 0; c < 2; ++c)
#pragma unroll
            for (int r = 0; r < 16; ++r) {
                int dm = (r & 3) + 8 * (r >> 2) + 4 * h;
                if (MODE == 1) {
                    int x  = x0 + a * 32 + dm;
                    int co = c * 32 + i31;
                    Out[((size_t)(b * OH + om) * WW + x) * 64 + co] = (_Float16)acc[a][c][r];
                } else {
                    int co = a * 32 + dm;
                    int x  = x0 + c * 32 + i31;
                    Out[((size_t)(b * 64 + co) * OH + om) * WW + x] = (_Float16)acc[a][c][r];
                }
            }
}

// ---------------------------------------------------------------------------
// blend1: C[b][96][320][64] + T[b][16][320][64] -> Xt2[b][96][320][64] (f16)
// Full-cache-line blocks: one block = ALL 64 co x 4 x x all 96 y.
// grid (80 xt, 4 b), block 256 = 8 co8 x 4 xl x 8 yt. LDS 57 KB.
// ---------------------------------------------------------------------------
__global__ __launch_bounds__(256) void blend1_kernel(
    const _Float16* __restrict__ Cb, const _Float16* __restrict__ T,
    const float* __restrict__ bias, _Float16* __restrict__ Xt2, ShiftInfo si)
{
    __shared__ __align__(16) _Float16 Cs[96 * 4 * 64];   // [row][xl][co] 49 KB
    __shared__ __align__(16) _Float16 Ts[16 * 4 * 64];   // 8 KB
    const int xt = blockIdx.x, b = blockIdx.y, t = threadIdx.x;
    const int x0 = xt * 4;
    const half8_t z = {0,0,0,0,0,0,0,0};

    for (int u = t; u < 96 * 32; u += 256) {
        int row = u >> 5, v = u & 31;        // v = xl*8 + c8
        *(half8_t*)&Cs[(row * 32 + v) * 8] =
            *(const half8_t*)&Cb[((size_t)(b * HH + row) * WW + x0 + (v >> 3)) * 64 + (v & 7) * 8];
    }
    for (int u = t; u < 16 * 32; u += 256) {
        int row = u >> 5, v = u & 31;
        *(half8_t*)&Ts[(row * 32 + v) * 8] =
            *(const half8_t*)&T[((size_t)(b * 16 + row) * WW + x0 + (v >> 3)) * 64 + (v & 7) * 8];
    }
    __syncthreads();

    const int co8 = t & 7, xl = (t >> 3) & 3, yt = t >> 5;
    half8_t bv;
#pragma unroll
    for (int j = 0; j < 8; ++j) bv[j] = (_Float16)bias[co8 * 8 + j];

    const int y0 = yt * 12;
    half8_t cur[NP];
#pragma unroll
    for (int d = 0; d < NP; ++d) {
        int r = y0 + si.s0[d] - 1;
        cur[d] = (r < HH) ? *(const half8_t*)&Cs[((r * 4 + xl) * 64) + co8 * 8] : z;
    }
    for (int y = y0; y < y0 + 12; ++y) {
        half8_t m = z;
#pragma unroll
        for (int d = 0; d < NP; ++d) {
            int r1 = y + si.s0[d];
            half8_t v1 = (r1 < HH) ? *(const half8_t*)&Cs[((r1 * 4 + xl) * 64) + co8 * 8] : z;
            half8_t v0 = cur[d];
            cur[d] = v1;
            _Float16 a = (_Float16)si.wa[d], wg = (_Float16)si.wb[d];
            half8_t p;
            if (y == 0) {
                half8_t t0 = *(const half8_t*)&Ts[(((2 * d) * 4 + xl) * 64) + co8 * 8];
                half8_t t1 = *(const half8_t*)&Ts[(((2 * d + 1) * 4 + xl) * 64) + co8 * 8];
                p = a * (v0 - t0) + wg * (v1 - t1);
            } else {
                p = a * v0 + wg * v1;
            }
            m = (d == 0) ? p : __builtin_elementwise_max(m, p);
        }
        half8_t o = __builtin_elementwise_max(m + bv, z);
        *(half8_t*)&Xt2[((size_t)(b * HH + y) * WW + x0 + xl) * 64 + co8 * 8] = o;
    }
}

// ---------------------------------------------------------------------------
// blend2: C[b][64][96][320] + T[b][64][16][320] -> Out fp32 [b][64][96][320]
// grid 1280 = (xt 5) x (co 64) x (b 4), block 256.
// ---------------------------------------------------------------------------
__global__ __launch_bounds__(256) void blend2_kernel(
    const _Float16* __restrict__ Cb, const _Float16* __restrict__ T,
    const float* __restrict__ bias, float* __restrict__ Out, ShiftInfo si)
{
    __shared__ __align__(16) _Float16 Cs[96 * 64];
    __shared__ __align__(16) _Float16 Ts[16 * 64];
    const int task = blockIdx.x, t = threadIdx.x;
    const int xt = task % 5;
    const int rem = task / 5;
    const int co = rem & 63;
    const int b  = rem >> 6;
    const int x0 = xt * 64;
    const half8_t z = {0,0,0,0,0,0,0,0};

    for (int u = t; u < 96 * 8; u += 256) {
        int row = u >> 3, x8 = u & 7;
        *(half8_t*)&Cs[row * 64 + x8 * 8] =
            *(const half8_t*)&Cb[((size_t)(b * 64 + co) * HH + row) * WW + x0 + x8 * 8];
    }
    for (int u = t; u < 16 * 8; u += 256) {
        int row = u >> 3, x8 = u & 7;
        *(half8_t*)&Ts[row * 64 + x8 * 8] =
            *(const half8_t*)&T[((size_t)(b * 64 + co) * 16 + row) * WW + x0 + x8 * 8];
    }
    __syncthreads();

    const int x8 = t & 7, yt = t >> 3;
    const float bvf = bias[co];
    const int y0 = yt * 3;

    half8_t cur[NP];
#pragma unroll
    for (int d = 0; d < NP; ++d) {
        int r = y0 + si.s0[d] - 1;
        cur[d] = (r < HH) ? *(const half8_t*)&Cs[r * 64 + x8 * 8] : z;
    }
    for (int y = y0; y < y0 + 3; ++y) {
        half8_t m = z;
#pragma unroll
        for (int d = 0; d < NP; ++d) {
            int r1 = y + si.s0[d];
            half8_t v1 = (r1 < HH) ? *(const half8_t*)&Cs[r1 * 64 + x8 * 8] : z;
            half8_t v0 = cur[d];
            cur[d] = v1;
            _Float16 a = (_Float16)si.wa[d], wg = (_Float16)si.wb[d];
            half8_t p;
            if (y == 0) {
                half8_t t0 = *(const half8_t*)&Ts[(2 * d) * 64 + x8 * 8];
                half8_t t1 = *(const half8_t*)&Ts[(2 * d + 1) * 64 + x8 * 8];
                p = a * (v0 - t0) + wg * (v1 - t1);
            } else {
                p = a * v0 + wg * v1;
            }
            m = (d == 0) ? p : __builtin_elementwise_max(m, p);
        }
        float4 o0, o1;
        o0.x = fmaxf((float)m[0] + bvf, 0.f);
        o0.y = fmaxf((float)m[1] + bvf, 0.f);
        o0.z = fmaxf((float)m[2] + bvf, 0.f);
        o0.w = fmaxf((float)m[3] + bvf, 0.f);
        o1.x = fmaxf((float)m[4] + bvf, 0.f);
        o1.y = fmaxf((float)m[5] + bvf, 0.f);
        o1.z = fmaxf((float)m[6] + bvf, 0.f);
        o1.w = fmaxf((float)m[7] + bvf, 0.f);
        float* op = Out + ((size_t)(b * 64 + co) * HH + y) * WW + x0 + x8 * 8;
        *(float4*)op = o0;
        *(float4*)(op + 4) = o1;
    }
}

// ---------------------------------------------------------------------------
extern "C" void kernel_launch(void* const* d_in, const int* in_sizes, int n_in,
                              void* d_out, int out_size, void* d_ws, size_t ws_size,
                              hipStream_t stream) {
    const float* x  = (const float*)d_in[0];
    const float* W1 = (const float*)d_in[1];
    const float* b1 = (const float*)d_in[2];
    const float* W2 = (const float*)d_in[3];
    const float* b2 = (const float*)d_in[4];
    float* out = (float*)d_out;

    _Float16* Xt1 = (_Float16*)d_ws;            // 7,864,320 halves
    _Float16* Cb  = Xt1 + 7864320;              // 7,864,320
    _Float16* T   = Cb  + 7864320;              // 1,310,720
    _Float16* Wf  = T   + 1310720;              // 73,728 (both layers, MFMA layout)
    _Float16* Xt2 = (_Float16*)d_out;           // f16 scratch inside d_out

    ShiftInfo si;
    for (int d = 0; d < NP; ++d) {
        double disp = 0.02 + d * (0.98 / 7.0);
        double sh   = 76.0 * disp;
        int s0      = (int)floor(sh);
        double w    = sh - (double)s0;
        si.s0[d] = s0;
        si.wa[d] = (float)(1.0 - w);
        si.wb[d] = (float)w;
        si.rows[2 * d]     = s0 - 1;
        si.rows[2 * d + 1] = s0;
    }

    prep_kernel<<<dim3(402), 256, 0, stream>>>(x, W1, W2, Xt1, Wf);

    conv_kernel<1><<<dim3(5, 28, 4), 256, 0, stream>>>(Xt1, Wf, Cb, T, si);
    blend1_kernel<<<dim3(80, 4), 256, 0, stream>>>(Cb, T, b1, Xt2, si);

    conv_kernel<2><<<dim3(5, 28, 4), 256, 0, stream>>>(Xt2, Wf + 36864, Cb, T, si);
    blend2_kernel<<<dim3(1280), 256, 0, stream>>>(Cb, T, b2, out, si);
}